// Round 7
// baseline (972.598 us; speedup 1.0000x reference)
//
#include <hip/hip_runtime.h>
#include <cstdint>
#include <cstddef>

#define NROWS 16384
#define DDIM  256
#define KCODES 8192
#define MARGIN 1.5f

typedef short bf16x8 __attribute__((ext_vector_type(8)));
typedef float f32x4 __attribute__((ext_vector_type(4)));
typedef float f32x2 __attribute__((ext_vector_type(2)));

__device__ inline unsigned short f2bf(float f) {
  unsigned int u = __float_as_uint(f);
  return (unsigned short)((u + 0x7fffu + ((u >> 16) & 1u)) >> 16);  // RNE
}

// full top-2 insert with (val, index) total order — used only in butterflies
__device__ inline void ins2(float v, int i, float& v1, int& i1, float& v2, int& i2) {
  bool b1 = (v < v1) || (v == v1 && i < i1);
  bool b2 = (v < v2) || (v == v2 && i < i2);
  if (b1) { v2 = v1; i2 = i1; v1 = v; i1 = i; }
  else if (b2) { v2 = v; i2 = i; }
}

// ---------------------------------------------------------------------------
// K0: X rows -> Xb (bf16 row-major) + x2 ; E rows -> Ebt (bf16, MFMA B-frag
// layout: elem(c,k) at ct*4096 + kq*512 + lc*32 + (k&31)) + e2. One wave/row.
// ---------------------------------------------------------------------------
__global__ void k_prep(const float* __restrict__ inp, const float* __restrict__ emb,
                       unsigned short* __restrict__ Xb, unsigned short* __restrict__ Ebt,
                       float* __restrict__ x2, float* __restrict__ e2) {
  int wave = threadIdx.x >> 6, lane = threadIdx.x & 63;
  int row = blockIdx.x * 4 + wave;
  bool isx = row < NROWS;
  const float* src = isx ? (inp + (size_t)row * DDIM) : (emb + (size_t)(row - NROWS) * DDIM);
  float4 v = ((const float4*)src)[lane];
  ushort4 u; u.x = f2bf(v.x); u.y = f2bf(v.y); u.z = f2bf(v.z); u.w = f2bf(v.w);
  if (isx) {
    *(ushort4*)&Xb[(size_t)row * DDIM + lane * 4] = u;
  } else {
    int c = row - NROWS, ct = c >> 4, lc = c & 15;
    size_t off = (size_t)ct * 4096 + (lane >> 3) * 512 + lc * 32 + (lane & 7) * 4;
    *(ushort4*)&Ebt[off] = u;
  }
  float s = v.x * v.x + v.y * v.y + v.z * v.z + v.w * v.w;
#pragma unroll
  for (int o = 32; o >= 1; o >>= 1) s += __shfl_down(s, o, 64);
  if (lane == 0) { if (isx) x2[row] = s; else e2[row - NROWS] = s; }
}

// ---------------------------------------------------------------------------
// K1: barrier-free distance scan, fully scalarized (no scratch). Wave owns 32
// rows (A-frags in named VGPRs) and one 1024-col slice; streams B-frags
// global->reg, 16 MFMA/t, running per-row top-2 of d' = e2 - 2*dot.
// ---------------------------------------------------------------------------
#define DECL_SLOT(s) \
  float v1_##s = 3.4e38f, v2_##s = 3.4e38f; \
  int i1_##s = 0x7fffffff, i2_##s = 0x7fffffff;

#define UPD(s, a) { \
  float d = fmaf(-2.0f, (a), e2c); \
  if (d < v1_##s) { v2_##s = v1_##s; i2_##s = i1_##s; v1_##s = d; i1_##s = col; } \
  else if (d < v2_##s) { v2_##s = d; i2_##s = col; } }

#define RED_SLOT(s, mi, r) { \
  float a1 = v1_##s, a2 = v2_##s; int b1 = i1_##s, b2 = i2_##s; \
  for (int off = 1; off < 16; off <<= 1) { \
    float o1 = __shfl_xor(a1, off, 64); int p1 = __shfl_xor(b1, off, 64); \
    float o2 = __shfl_xor(a2, off, 64); int p2 = __shfl_xor(b2, off, 64); \
    ins2(o1, p1, a1, b1, a2, b2); ins2(o2, p2, a1, b1, a2, b2); } \
  if (lcol == 0) { \
    int row = row0 + (mi) * 16 + quad * 4 + (r); \
    size_t o = ((size_t)row * 8 + slice) * 2; \
    candv[o] = a1; candv[o + 1] = a2; candi[o] = b1; candi[o + 1] = b2; } }

__global__ __launch_bounds__(256, 2) void k_dist(
    const unsigned short* __restrict__ Xb, const unsigned short* __restrict__ Ebt,
    const float* __restrict__ e2,
    float* __restrict__ candv, int* __restrict__ candi) {
  const int lane = threadIdx.x & 63;
  const int w = threadIdx.x >> 6;
  const int lcol = lane & 15, quad = lane >> 4;
  const int row0 = (blockIdx.x >> 3) * 128 + w * 32;
  const int slice = blockIdx.x & 7;

  const unsigned short* ApA = Xb + (size_t)(row0 + lcol) * DDIM + quad * 8;
  const unsigned short* ApB = ApA + 16 * DDIM;
#define DECL_A(q) \
  bf16x8 A0_##q = *(const bf16x8*)(ApA + (q) * 32); \
  bf16x8 A1_##q = *(const bf16x8*)(ApB + (q) * 32);
  DECL_A(0) DECL_A(1) DECL_A(2) DECL_A(3) DECL_A(4) DECL_A(5) DECL_A(6) DECL_A(7)

  DECL_SLOT(0) DECL_SLOT(1) DECL_SLOT(2) DECL_SLOT(3)
  DECL_SLOT(4) DECL_SLOT(5) DECL_SLOT(6) DECL_SLOT(7)

  const unsigned short* Bbase = Ebt + (size_t)slice * 64 * 4096 + lcol * 32 + quad * 8;
  const float* e2p = e2 + slice * 1024 + lcol;
  const int colbase = slice * 1024 + lcol;

#pragma unroll 2
  for (int t = 0; t < 64; ++t) {
    const unsigned short* Bt = Bbase + (size_t)t * 4096;
    bf16x8 B0 = *(const bf16x8*)(Bt);
    bf16x8 B1 = *(const bf16x8*)(Bt + 512);
    bf16x8 B2 = *(const bf16x8*)(Bt + 1024);
    bf16x8 B3 = *(const bf16x8*)(Bt + 1536);
    bf16x8 B4 = *(const bf16x8*)(Bt + 2048);
    bf16x8 B5 = *(const bf16x8*)(Bt + 2560);
    bf16x8 B6 = *(const bf16x8*)(Bt + 3072);
    bf16x8 B7 = *(const bf16x8*)(Bt + 3584);
    float e2c = e2p[t * 16];
    f32x4 acc0 = {0.f, 0.f, 0.f, 0.f};
    f32x4 acc1 = {0.f, 0.f, 0.f, 0.f};
#define MM(q) \
    acc0 = __builtin_amdgcn_mfma_f32_16x16x32_bf16(A0_##q, B##q, acc0, 0, 0, 0); \
    acc1 = __builtin_amdgcn_mfma_f32_16x16x32_bf16(A1_##q, B##q, acc1, 0, 0, 0);
    MM(0) MM(1) MM(2) MM(3) MM(4) MM(5) MM(6) MM(7)
#undef MM
    const int col = colbase + t * 16;
    UPD(0, acc0[0]) UPD(1, acc0[1]) UPD(2, acc0[2]) UPD(3, acc0[3])
    UPD(4, acc1[0]) UPD(5, acc1[1]) UPD(6, acc1[2]) UPD(7, acc1[3])
  }

  // C/D layout: row = quad*4 + reg, col = lane&15
  RED_SLOT(0, 0, 0) RED_SLOT(1, 0, 1) RED_SLOT(2, 0, 2) RED_SLOT(3, 0, 3)
  RED_SLOT(4, 1, 0) RED_SLOT(5, 1, 1) RED_SLOT(6, 1, 2) RED_SLOT(7, 1, 3)
}

// ---------------------------------------------------------------------------
// K2: merged select + scatter. One wave per row: approx-min over 16 stored
// candidates, exact fp32 rescore within MARGIN (first-index ties), then
// quantized/STE write, counts/dw atomics, loss partial. nt on output stores.
// ---------------------------------------------------------------------------
__global__ void k_selscat(const float* __restrict__ inp, const float* __restrict__ emb,
                          const float* __restrict__ x2, const float* __restrict__ e2,
                          const float* __restrict__ candv, const int* __restrict__ candi,
                          int* __restrict__ idxb,
                          float* __restrict__ out_quant,
                          float* __restrict__ counts, float* __restrict__ dw,
                          float* __restrict__ loss_acc) {
  __shared__ float wsum[4];
  int w = threadIdx.x >> 6, lane = threadIdx.x & 63;
  int row = blockIdx.x * 4 + w;
  float cv = 3.4e38f;
  int ci = 0x7fffffff;
  if (lane < 16) { cv = candv[(size_t)row * 16 + lane]; ci = candi[(size_t)row * 16 + lane]; }
  float m = cv;
#pragma unroll
  for (int o = 32; o >= 1; o >>= 1) m = fminf(m, __shfl_xor(m, o, 64));
  float thr = m + MARGIN;
  unsigned long long b = __ballot(cv <= thr);
  float4 x = *(const float4*)(inp + (size_t)row * DDIM + lane * 4);
  float x2r = x2[row];
  float bestv = 3.4e38f;
  int besti = 0x7fffffff;
  while (b) {
    int src = __ffsll(b) - 1; b &= b - 1;
    int j = __shfl(ci, src, 64);
    float4 e4 = *(const float4*)(emb + (size_t)j * DDIM + lane * 4);
    float p = x.x * e4.x + x.y * e4.y + x.z * e4.z + x.w * e4.w;
#pragma unroll
    for (int o = 32; o >= 1; o >>= 1) p += __shfl_xor(p, o, 64);
    float d2 = (x2r + e2[j]) - 2.0f * p;  // mirror reference formula
    if (d2 < bestv || (d2 == bestv && j < besti)) { bestv = d2; besti = j; }
  }
  const int j = besti;  // identical on all lanes (xor reductions)
  if (lane == 0) idxb[row] = j;

  float4 e = *(const float4*)(emb + (size_t)j * DDIM + lane * 4);
  size_t qo = (size_t)row * DDIM + lane * 4;  // out_quant only 4B aligned
  __builtin_nontemporal_store(x.x + (e.x - x.x), out_quant + qo + 0);
  __builtin_nontemporal_store(x.y + (e.y - x.y), out_quant + qo + 1);
  __builtin_nontemporal_store(x.z + (e.z - x.z), out_quant + qo + 2);
  __builtin_nontemporal_store(x.w + (e.w - x.w), out_quant + qo + 3);
  size_t dwo = (size_t)j * DDIM + lane * 4;
  atomicAdd(&dw[dwo + 0], x.x);
  atomicAdd(&dw[dwo + 1], x.y);
  atomicAdd(&dw[dwo + 2], x.z);
  atomicAdd(&dw[dwo + 3], x.w);
  float d0 = e.x - x.x, d1 = e.y - x.y, d2 = e.z - x.z, d3 = e.w - x.w;
  float s = d0 * d0 + d1 * d1 + d2 * d2 + d3 * d3;
#pragma unroll
  for (int o = 32; o >= 1; o >>= 1) s += __shfl_down(s, o, 64);
  if (lane == 0) {
    atomicAdd(&counts[j], 1.0f);
    wsum[w] = s;
  }
  __syncthreads();
  if (threadIdx.x == 0) atomicAdd(loss_acc, wsum[0] + wsum[1] + wsum[2] + wsum[3]);
}

// ---------------------------------------------------------------------------
// K2b: encodings one-hot writer, nontemporal full-width stores.
// out_enc base is ≡8 mod 16 → head/tail f32x2, middle 2047 f32x4 (16B
// aligned). nt streams full lines, dodging the 4x write amplification seen
// on plain stores to d_out (R5: k_enc ≈ rocclr fill ≈ 1.6 TB/s payload).
// ---------------------------------------------------------------------------
__global__ __launch_bounds__(256) void k_enc(const int* __restrict__ idxb,
                                             float* __restrict__ out_enc) {
  const int row = blockIdx.x;
  const int tid = threadIdx.x;
  const int j = idxb[row];
  float* base = out_enc + (size_t)row * KCODES;
#pragma unroll
  for (int i = 0; i < 8; ++i) {
    int q = i * 256 + tid;          // 0..2047 float4-index; covers floats 2+4q..5+4q
    if (q < 2047) {
      int f0 = 2 + q * 4;
      f32x4 v;
      v[0] = (j == f0 + 0) ? 1.0f : 0.0f;
      v[1] = (j == f0 + 1) ? 1.0f : 0.0f;
      v[2] = (j == f0 + 2) ? 1.0f : 0.0f;
      v[3] = (j == f0 + 3) ? 1.0f : 0.0f;
      __builtin_nontemporal_store(v, (f32x4*)(base + f0));
    }
  }
  if (tid == 0) {
    f32x2 head = {j == 0 ? 1.0f : 0.0f, j == 1 ? 1.0f : 0.0f};
    f32x2 tail = {j == 8190 ? 1.0f : 0.0f, j == 8191 ? 1.0f : 0.0f};
    __builtin_nontemporal_store(head, (f32x2*)base);
    __builtin_nontemporal_store(tail, (f32x2*)(base + 8190));
  }
}

// ---------------------------------------------------------------------------
// K4: single block: n, normalized ecs, perplexity, loss.
// ---------------------------------------------------------------------------
__global__ void k_stats(const float* __restrict__ counts, const float* __restrict__ ema_cs,
                        const float* __restrict__ loss_acc,
                        float* __restrict__ out_loss, float* __restrict__ out_perp,
                        float* __restrict__ out_ecs) {
  __shared__ float red[8];
  int tid = threadIdx.x;
  float ln = 0.0f, lp = 0.0f;
  for (int k = tid; k < KCODES; k += 256) {
    float c = counts[k];
    float er = ema_cs[k] * 0.99f + 0.01f * c;
    ln += er;
    float p = c * (1.0f / 16384.0f);
    lp += p * logf(p + 1e-10f);
  }
  int lane = tid & 63, wave = tid >> 6;
#pragma unroll
  for (int o = 32; o >= 1; o >>= 1) {
    ln += __shfl_down(ln, o, 64);
    lp += __shfl_down(lp, o, 64);
  }
  if (lane == 0) { red[wave] = ln; red[wave + 4] = lp; }
  __syncthreads();
  float n = red[0] + red[1] + red[2] + red[3];
  float plsum = red[4] + red[5] + red[6] + red[7];
  float denom = n + 0.08192f;  // n + K*EPSILON
  for (int k = tid; k < KCODES; k += 256) {
    float c = counts[k];
    float er = ema_cs[k] * 0.99f + 0.01f * c;
    out_ecs[k] = (er + 1e-5f) / denom * n;  // mirror reference op order
  }
  if (tid == 0) {
    out_loss[0] = 0.25f * (loss_acc[0] / 4194304.0f);  // /(N*D)
    out_perp[0] = expf(-plsum);
  }
}

// ---------------------------------------------------------------------------
// K5: EMA update + new embedding (nt f32x2: outputs 8B-aligned).
// ---------------------------------------------------------------------------
__global__ void k_update(const float* __restrict__ ema_w, const float* __restrict__ dw,
                         const float* __restrict__ ecs,
                         float* __restrict__ out_emaw, float* __restrict__ out_emb) {
  size_t i = ((size_t)blockIdx.x * blockDim.x + threadIdx.x) * 4;
  int k = (int)(i >> 8);
  float4 w = *(const float4*)(ema_w + i);
  float4 d = *(const float4*)(dw + i);
  float ec = ecs[k];
  float nw0 = w.x * 0.99f + 0.01f * d.x;
  float nw1 = w.y * 0.99f + 0.01f * d.y;
  float nw2 = w.z * 0.99f + 0.01f * d.z;
  float nw3 = w.w * 0.99f + 0.01f * d.w;
  f32x2 a0 = {nw0, nw1}, a1 = {nw2, nw3};
  f32x2 b0 = {nw0 / ec, nw1 / ec}, b1 = {nw2 / ec, nw3 / ec};
  __builtin_nontemporal_store(a0, (f32x2*)(out_emaw + i));
  __builtin_nontemporal_store(a1, (f32x2*)(out_emaw + i + 2));
  __builtin_nontemporal_store(b0, (f32x2*)(out_emb + i));
  __builtin_nontemporal_store(b1, (f32x2*)(out_emb + i + 2));
}

extern "C" void kernel_launch(void* const* d_in, const int* in_sizes, int n_in,
                              void* d_out, int out_size, void* d_ws, size_t ws_size,
                              hipStream_t stream) {
  const float* inp = (const float*)d_in[0];
  const float* emb = (const float*)d_in[1];
  const float* emacs = (const float*)d_in[2];
  const float* emaw = (const float*)d_in[3];

  float* out = (float*)d_out;
  float* out_loss = out;                                   // [1]
  float* out_quant = out + 1;                              // [N*D]
  float* out_perp = out_quant + (size_t)NROWS * DDIM;      // [1]
  float* out_enc = out_perp + 1;                           // [N*K]
  float* out_emb = out_enc + (size_t)NROWS * KCODES;       // [K*D]
  float* out_ecs = out_emb + (size_t)KCODES * DDIM;        // [K]
  float* out_emaw = out_ecs + KCODES;                      // [K*D]

  // Workspace (~22.3 MB)
  char* p = (char*)d_ws;
  unsigned short* Xb = (unsigned short*)p; p += (size_t)NROWS * DDIM * 2;   // 8 MB
  unsigned short* Ebt = (unsigned short*)p; p += (size_t)KCODES * DDIM * 2; // 4 MB
  float* x2 = (float*)p; p += (size_t)NROWS * 4;
  float* e2 = (float*)p; p += (size_t)KCODES * 4;
  float* candv = (float*)p; p += (size_t)NROWS * 16 * 4;                    // 1 MB
  int* candi = (int*)p; p += (size_t)NROWS * 16 * 4;                        // 1 MB
  float* dw = (float*)p; p += (size_t)KCODES * DDIM * 4;                    // 8 MB
  float* counts = (float*)p; p += (size_t)KCODES * 4;
  float* loss_acc = (float*)p; p += 16;
  int* idxb = (int*)p; p += (size_t)NROWS * 4;

  (void)hipMemsetAsync(dw, 0, ((size_t)KCODES * DDIM + KCODES + 4) * sizeof(float), stream);

  k_prep<<<(NROWS + KCODES) / 4, 256, 0, stream>>>(inp, emb, Xb, Ebt, x2, e2);
  k_dist<<<1024, 256, 0, stream>>>(Xb, Ebt, e2, candv, candi);
  k_selscat<<<NROWS / 4, 256, 0, stream>>>(inp, emb, x2, e2, candv, candi, idxb,
                                           out_quant, counts, dw, loss_acc);
  k_enc<<<NROWS, 256, 0, stream>>>(idxb, out_enc);
  k_stats<<<1, 256, 0, stream>>>(counts, emacs, loss_acc, out_loss, out_perp, out_ecs);
  k_update<<<(KCODES * DDIM) / 1024, 256, 0, stream>>>(emaw, dw, out_ecs, out_emaw, out_emb);
}

// Round 8
// 927.797 us; speedup vs baseline: 1.0483x; 1.0483x over previous
//
#include <hip/hip_runtime.h>
#include <cstdint>
#include <cstddef>

#define NROWS 16384
#define DDIM  256
#define KCODES 8192
#define MARGIN 1.5f

typedef short bf16x8 __attribute__((ext_vector_type(8)));
typedef float f32x4 __attribute__((ext_vector_type(4)));
typedef float f32x2 __attribute__((ext_vector_type(2)));

__device__ inline unsigned short f2bf(float f) {
  unsigned int u = __float_as_uint(f);
  return (unsigned short)((u + 0x7fffu + ((u >> 16) & 1u)) >> 16);  // RNE
}

__device__ inline void gl_lds16(const void* g, void* l) {
  __builtin_amdgcn_global_load_lds(
      (const __attribute__((address_space(1))) unsigned int*)g,
      (__attribute__((address_space(3))) unsigned int*)l, 16, 0, 0);
}

// full top-2 insert with (val, index) total order — used only in butterflies
__device__ inline void ins2(float v, int i, float& v1, int& i1, float& v2, int& i2) {
  bool b1 = (v < v1) || (v == v1 && i < i1);
  bool b2 = (v < v2) || (v == v2 && i < i2);
  if (b1) { v2 = v1; i2 = i1; v1 = v; i1 = i; }
  else if (b2) { v2 = v; i2 = i; }
}

// ---------------------------------------------------------------------------
// K0: X rows -> Xb (bf16 row-major) + x2 ; E rows -> Ebt (bf16, MFMA B-frag
// layout: elem(c,k) at ct*4096 + kq*512 + lc*32 + (k&31)) + e2. One wave/row.
// ---------------------------------------------------------------------------
__global__ void k_prep(const float* __restrict__ inp, const float* __restrict__ emb,
                       unsigned short* __restrict__ Xb, unsigned short* __restrict__ Ebt,
                       float* __restrict__ x2, float* __restrict__ e2) {
  int wave = threadIdx.x >> 6, lane = threadIdx.x & 63;
  int row = blockIdx.x * 4 + wave;
  bool isx = row < NROWS;
  const float* src = isx ? (inp + (size_t)row * DDIM) : (emb + (size_t)(row - NROWS) * DDIM);
  float4 v = ((const float4*)src)[lane];
  ushort4 u; u.x = f2bf(v.x); u.y = f2bf(v.y); u.z = f2bf(v.z); u.w = f2bf(v.w);
  if (isx) {
    *(ushort4*)&Xb[(size_t)row * DDIM + lane * 4] = u;
  } else {
    int c = row - NROWS, ct = c >> 4, lc = c & 15;
    size_t off = (size_t)ct * 4096 + (lane >> 3) * 512 + lc * 32 + (lane & 7) * 4;
    *(ushort4*)&Ebt[off] = u;
  }
  float s = v.x * v.x + v.y * v.y + v.z * v.z + v.w * v.w;
#pragma unroll
  for (int o = 32; o >= 1; o >>= 1) s += __shfl_down(s, o, 64);
  if (lane == 0) { if (isx) x2[row] = s; else e2[row - NROWS] = s; }
}

// ---------------------------------------------------------------------------
// K1 v3: LDS-shared B-slice distance scan. Block = 128 rows x 1 slice (1024
// cols); 4 waves share each 8KB B-tile (16 cols x K=256) staged once per
// t-step via global_load_lds into a double buffer (prefetch issued AFTER the
// barrier -> full iteration of latency cover; 4 blocks/CU overlap stalls).
// Global B traffic: 0.5 GB total (was 2 GB register-streamed). Per-row top-2
// of d' = e2 - 2*dot kept in named scalars (no scratch).
// ---------------------------------------------------------------------------
#define DECL_SLOT(s) \
  float v1_##s = 3.4e38f, v2_##s = 3.4e38f; \
  int i1_##s = 0x7fffffff, i2_##s = 0x7fffffff;

#define UPD(s, a) { \
  float d = fmaf(-2.0f, (a), e2c); \
  if (d < v1_##s) { v2_##s = v1_##s; i2_##s = i1_##s; v1_##s = d; i1_##s = col; } \
  else if (d < v2_##s) { v2_##s = d; i2_##s = col; } }

#define RED_SLOT(s, mi, r) { \
  float a1 = v1_##s, a2 = v2_##s; int b1 = i1_##s, b2 = i2_##s; \
  for (int off = 1; off < 16; off <<= 1) { \
    float o1 = __shfl_xor(a1, off, 64); int p1 = __shfl_xor(b1, off, 64); \
    float o2 = __shfl_xor(a2, off, 64); int p2 = __shfl_xor(b2, off, 64); \
    ins2(o1, p1, a1, b1, a2, b2); ins2(o2, p2, a1, b1, a2, b2); } \
  if (lcol == 0) { \
    int row = row0 + (mi) * 16 + quad * 4 + (r); \
    size_t o = ((size_t)row * 8 + slice) * 2; \
    candv[o] = a1; candv[o + 1] = a2; candi[o] = b1; candi[o + 1] = b2; } }

__global__ __launch_bounds__(256, 2) void k_dist(
    const unsigned short* __restrict__ Xb, const unsigned short* __restrict__ Ebt,
    const float* __restrict__ e2,
    float* __restrict__ candv, int* __restrict__ candi) {
  __shared__ unsigned short Bs[2][4096];  // 2 x 8KB double buffer
  __shared__ float se2[1024];             // 4KB: slice's e2
  const int tid = threadIdx.x;
  const int lane = tid & 63;
  const int w = tid >> 6;
  const int lcol = lane & 15, quad = lane >> 4;
  const int rt = blockIdx.x >> 3, slice = blockIdx.x & 7;
  const int row0 = rt * 128 + w * 32;

  // stage e2 slice: 256 threads x 16B
  ((float4*)se2)[tid] = ((const float4*)(e2 + slice * 1024))[tid];

  const unsigned short* ApA = Xb + (size_t)(row0 + lcol) * DDIM + quad * 8;
  const unsigned short* ApB = ApA + 16 * DDIM;
#define DECL_A(q) \
  bf16x8 A0_##q = *(const bf16x8*)(ApA + (q) * 32); \
  bf16x8 A1_##q = *(const bf16x8*)(ApB + (q) * 32);
  DECL_A(0) DECL_A(1) DECL_A(2) DECL_A(3) DECL_A(4) DECL_A(5) DECL_A(6) DECL_A(7)

  DECL_SLOT(0) DECL_SLOT(1) DECL_SLOT(2) DECL_SLOT(3)
  DECL_SLOT(4) DECL_SLOT(5) DECL_SLOT(6) DECL_SLOT(7)

  const unsigned short* Ebase = Ebt + (size_t)(slice * 64) * 4096;
  const int inst0 = w * 2, inst1 = w * 2 + 1;  // 8 x 1KB staging instrs / block

  // prologue: stage t=0 into buf 0
  gl_lds16(Ebase + inst0 * 512 + lane * 8, &Bs[0][inst0 * 512]);
  gl_lds16(Ebase + inst1 * 512 + lane * 8, &Bs[0][inst1 * 512]);

  const int colbase = slice * 1024 + lcol;
  int buf = 0;
  for (int t = 0; t < 64; ++t) {
    __syncthreads();  // drains prefetch issued last iter (full iter in flight)
    if (t < 63) {
      const unsigned short* Eg = Ebase + (size_t)(t + 1) * 4096;
      gl_lds16(Eg + inst0 * 512 + lane * 8, &Bs[buf ^ 1][inst0 * 512]);
      gl_lds16(Eg + inst1 * 512 + lane * 8, &Bs[buf ^ 1][inst1 * 512]);
    }
    const unsigned short* Bt = &Bs[buf][0];
    const int laneoff = lcol * 32 + quad * 8;
    bf16x8 B0 = *(const bf16x8*)(Bt + laneoff);
    bf16x8 B1 = *(const bf16x8*)(Bt + 512 + laneoff);
    bf16x8 B2 = *(const bf16x8*)(Bt + 1024 + laneoff);
    bf16x8 B3 = *(const bf16x8*)(Bt + 1536 + laneoff);
    bf16x8 B4 = *(const bf16x8*)(Bt + 2048 + laneoff);
    bf16x8 B5 = *(const bf16x8*)(Bt + 2560 + laneoff);
    bf16x8 B6 = *(const bf16x8*)(Bt + 3072 + laneoff);
    bf16x8 B7 = *(const bf16x8*)(Bt + 3584 + laneoff);
    float e2c = se2[t * 16 + lcol];
    f32x4 acc0 = {0.f, 0.f, 0.f, 0.f};
    f32x4 acc1 = {0.f, 0.f, 0.f, 0.f};
#define MM(q) \
    acc0 = __builtin_amdgcn_mfma_f32_16x16x32_bf16(A0_##q, B##q, acc0, 0, 0, 0); \
    acc1 = __builtin_amdgcn_mfma_f32_16x16x32_bf16(A1_##q, B##q, acc1, 0, 0, 0);
    MM(0) MM(1) MM(2) MM(3) MM(4) MM(5) MM(6) MM(7)
#undef MM
    const int col = colbase + t * 16;
    UPD(0, acc0[0]) UPD(1, acc0[1]) UPD(2, acc0[2]) UPD(3, acc0[3])
    UPD(4, acc1[0]) UPD(5, acc1[1]) UPD(6, acc1[2]) UPD(7, acc1[3])
    buf ^= 1;
  }

  // C/D layout: row = quad*4 + reg, col = lane&15
  RED_SLOT(0, 0, 0) RED_SLOT(1, 0, 1) RED_SLOT(2, 0, 2) RED_SLOT(3, 0, 3)
  RED_SLOT(4, 1, 0) RED_SLOT(5, 1, 1) RED_SLOT(6, 1, 2) RED_SLOT(7, 1, 3)
}

// ---------------------------------------------------------------------------
// K2: merged select + scatter. One wave per row: approx-min over 16 stored
// candidates, exact fp32 rescore within MARGIN (first-index ties), then
// quantized/STE write, counts/dw atomics, loss partial.
// ---------------------------------------------------------------------------
__global__ void k_selscat(const float* __restrict__ inp, const float* __restrict__ emb,
                          const float* __restrict__ x2, const float* __restrict__ e2,
                          const float* __restrict__ candv, const int* __restrict__ candi,
                          int* __restrict__ idxb,
                          float* __restrict__ out_quant,
                          float* __restrict__ counts, float* __restrict__ dw,
                          float* __restrict__ loss_acc) {
  __shared__ float wsum[4];
  int w = threadIdx.x >> 6, lane = threadIdx.x & 63;
  int row = blockIdx.x * 4 + w;
  float cv = 3.4e38f;
  int ci = 0x7fffffff;
  if (lane < 16) { cv = candv[(size_t)row * 16 + lane]; ci = candi[(size_t)row * 16 + lane]; }
  float m = cv;
#pragma unroll
  for (int o = 32; o >= 1; o >>= 1) m = fminf(m, __shfl_xor(m, o, 64));
  float thr = m + MARGIN;
  unsigned long long b = __ballot(cv <= thr);
  float4 x = *(const float4*)(inp + (size_t)row * DDIM + lane * 4);
  float x2r = x2[row];
  float bestv = 3.4e38f;
  int besti = 0x7fffffff;
  while (b) {
    int src = __ffsll(b) - 1; b &= b - 1;
    int j = __shfl(ci, src, 64);
    float4 e4 = *(const float4*)(emb + (size_t)j * DDIM + lane * 4);
    float p = x.x * e4.x + x.y * e4.y + x.z * e4.z + x.w * e4.w;
#pragma unroll
    for (int o = 32; o >= 1; o >>= 1) p += __shfl_xor(p, o, 64);
    float d2 = (x2r + e2[j]) - 2.0f * p;  // mirror reference formula
    if (d2 < bestv || (d2 == bestv && j < besti)) { bestv = d2; besti = j; }
  }
  const int j = besti;  // identical on all lanes (xor reductions)
  if (lane == 0) idxb[row] = j;

  float4 e = *(const float4*)(emb + (size_t)j * DDIM + lane * 4);
  size_t qo = (size_t)row * DDIM + lane * 4;  // out_quant only 4B aligned
  __builtin_nontemporal_store(x.x + (e.x - x.x), out_quant + qo + 0);
  __builtin_nontemporal_store(x.y + (e.y - x.y), out_quant + qo + 1);
  __builtin_nontemporal_store(x.z + (e.z - x.z), out_quant + qo + 2);
  __builtin_nontemporal_store(x.w + (e.w - x.w), out_quant + qo + 3);
  size_t dwo = (size_t)j * DDIM + lane * 4;
  atomicAdd(&dw[dwo + 0], x.x);
  atomicAdd(&dw[dwo + 1], x.y);
  atomicAdd(&dw[dwo + 2], x.z);
  atomicAdd(&dw[dwo + 3], x.w);
  float d0 = e.x - x.x, d1 = e.y - x.y, d2 = e.z - x.z, d3 = e.w - x.w;
  float s = d0 * d0 + d1 * d1 + d2 * d2 + d3 * d3;
#pragma unroll
  for (int o = 32; o >= 1; o >>= 1) s += __shfl_down(s, o, 64);
  if (lane == 0) {
    atomicAdd(&counts[j], 1.0f);
    wsum[w] = s;
  }
  __syncthreads();
  if (threadIdx.x == 0) atomicAdd(loss_acc, wsum[0] + wsum[1] + wsum[2] + wsum[3]);
}

// ---------------------------------------------------------------------------
// K2b: encodings one-hot writer (nt full-width stores; base ≡8 mod 16).
// ---------------------------------------------------------------------------
__global__ __launch_bounds__(256) void k_enc(const int* __restrict__ idxb,
                                             float* __restrict__ out_enc) {
  const int row = blockIdx.x;
  const int tid = threadIdx.x;
  const int j = idxb[row];
  float* base = out_enc + (size_t)row * KCODES;
#pragma unroll
  for (int i = 0; i < 8; ++i) {
    int q = i * 256 + tid;          // 0..2047 float4-index; covers floats 2+4q..5+4q
    if (q < 2047) {
      int f0 = 2 + q * 4;
      f32x4 v;
      v[0] = (j == f0 + 0) ? 1.0f : 0.0f;
      v[1] = (j == f0 + 1) ? 1.0f : 0.0f;
      v[2] = (j == f0 + 2) ? 1.0f : 0.0f;
      v[3] = (j == f0 + 3) ? 1.0f : 0.0f;
      __builtin_nontemporal_store(v, (f32x4*)(base + f0));
    }
  }
  if (tid == 0) {
    f32x2 head = {j == 0 ? 1.0f : 0.0f, j == 1 ? 1.0f : 0.0f};
    f32x2 tail = {j == 8190 ? 1.0f : 0.0f, j == 8191 ? 1.0f : 0.0f};
    __builtin_nontemporal_store(head, (f32x2*)base);
    __builtin_nontemporal_store(tail, (f32x2*)(base + 8190));
  }
}

// ---------------------------------------------------------------------------
// K4: single block: n, normalized ecs, perplexity, loss.
// ---------------------------------------------------------------------------
__global__ void k_stats(const float* __restrict__ counts, const float* __restrict__ ema_cs,
                        const float* __restrict__ loss_acc,
                        float* __restrict__ out_loss, float* __restrict__ out_perp,
                        float* __restrict__ out_ecs) {
  __shared__ float red[8];
  int tid = threadIdx.x;
  float ln = 0.0f, lp = 0.0f;
  for (int k = tid; k < KCODES; k += 256) {
    float c = counts[k];
    float er = ema_cs[k] * 0.99f + 0.01f * c;
    ln += er;
    float p = c * (1.0f / 16384.0f);
    lp += p * logf(p + 1e-10f);
  }
  int lane = tid & 63, wave = tid >> 6;
#pragma unroll
  for (int o = 32; o >= 1; o >>= 1) {
    ln += __shfl_down(ln, o, 64);
    lp += __shfl_down(lp, o, 64);
  }
  if (lane == 0) { red[wave] = ln; red[wave + 4] = lp; }
  __syncthreads();
  float n = red[0] + red[1] + red[2] + red[3];
  float plsum = red[4] + red[5] + red[6] + red[7];
  float denom = n + 0.08192f;  // n + K*EPSILON
  for (int k = tid; k < KCODES; k += 256) {
    float c = counts[k];
    float er = ema_cs[k] * 0.99f + 0.01f * c;
    out_ecs[k] = (er + 1e-5f) / denom * n;  // mirror reference op order
  }
  if (tid == 0) {
    out_loss[0] = 0.25f * (loss_acc[0] / 4194304.0f);  // /(N*D)
    out_perp[0] = expf(-plsum);
  }
}

// ---------------------------------------------------------------------------
// K5: EMA update + new embedding (nt f32x2: outputs 8B-aligned).
// ---------------------------------------------------------------------------
__global__ void k_update(const float* __restrict__ ema_w, const float* __restrict__ dw,
                         const float* __restrict__ ecs,
                         float* __restrict__ out_emaw, float* __restrict__ out_emb) {
  size_t i = ((size_t)blockIdx.x * blockDim.x + threadIdx.x) * 4;
  int k = (int)(i >> 8);
  float4 w = *(const float4*)(ema_w + i);
  float4 d = *(const float4*)(dw + i);
  float ec = ecs[k];
  float nw0 = w.x * 0.99f + 0.01f * d.x;
  float nw1 = w.y * 0.99f + 0.01f * d.y;
  float nw2 = w.z * 0.99f + 0.01f * d.z;
  float nw3 = w.w * 0.99f + 0.01f * d.w;
  f32x2 a0 = {nw0, nw1}, a1 = {nw2, nw3};
  f32x2 b0 = {nw0 / ec, nw1 / ec}, b1 = {nw2 / ec, nw3 / ec};
  __builtin_nontemporal_store(a0, (f32x2*)(out_emaw + i));
  __builtin_nontemporal_store(a1, (f32x2*)(out_emaw + i + 2));
  __builtin_nontemporal_store(b0, (f32x2*)(out_emb + i));
  __builtin_nontemporal_store(b1, (f32x2*)(out_emb + i + 2));
}

extern "C" void kernel_launch(void* const* d_in, const int* in_sizes, int n_in,
                              void* d_out, int out_size, void* d_ws, size_t ws_size,
                              hipStream_t stream) {
  const float* inp = (const float*)d_in[0];
  const float* emb = (const float*)d_in[1];
  const float* emacs = (const float*)d_in[2];
  const float* emaw = (const float*)d_in[3];

  float* out = (float*)d_out;
  float* out_loss = out;                                   // [1]
  float* out_quant = out + 1;                              // [N*D]
  float* out_perp = out_quant + (size_t)NROWS * DDIM;      // [1]
  float* out_enc = out_perp + 1;                           // [N*K]
  float* out_emb = out_enc + (size_t)NROWS * KCODES;       // [K*D]
  float* out_ecs = out_emb + (size_t)KCODES * DDIM;        // [K]
  float* out_emaw = out_ecs + KCODES;                      // [K*D]

  // Workspace (~22.3 MB)
  char* p = (char*)d_ws;
  unsigned short* Xb = (unsigned short*)p; p += (size_t)NROWS * DDIM * 2;   // 8 MB
  unsigned short* Ebt = (unsigned short*)p; p += (size_t)KCODES * DDIM * 2; // 4 MB
  float* x2 = (float*)p; p += (size_t)NROWS * 4;
  float* e2 = (float*)p; p += (size_t)KCODES * 4;
  float* candv = (float*)p; p += (size_t)NROWS * 16 * 4;                    // 1 MB
  int* candi = (int*)p; p += (size_t)NROWS * 16 * 4;                        // 1 MB
  float* dw = (float*)p; p += (size_t)KCODES * DDIM * 4;                    // 8 MB
  float* counts = (float*)p; p += (size_t)KCODES * 4;
  float* loss_acc = (float*)p; p += 16;
  int* idxb = (int*)p; p += (size_t)NROWS * 4;

  (void)hipMemsetAsync(dw, 0, ((size_t)KCODES * DDIM + KCODES + 4) * sizeof(float), stream);

  k_prep<<<(NROWS + KCODES) / 4, 256, 0, stream>>>(inp, emb, Xb, Ebt, x2, e2);
  k_dist<<<1024, 256, 0, stream>>>(Xb, Ebt, e2, candv, candi);
  k_selscat<<<NROWS / 4, 256, 0, stream>>>(inp, emb, x2, e2, candv, candi, idxb,
                                           out_quant, counts, dw, loss_acc);
  k_enc<<<NROWS, 256, 0, stream>>>(idxb, out_enc);
  k_stats<<<1, 256, 0, stream>>>(counts, emacs, loss_acc, out_loss, out_perp, out_ecs);
  k_update<<<(KCODES * DDIM) / 1024, 256, 0, stream>>>(emaw, dw, out_ecs, out_emaw, out_emb);
}